// Round 2
// baseline (1055.140 us; speedup 1.0000x reference)
//
#include <hip/hip_runtime.h>
#include <hip/hip_bf16.h>

typedef __attribute__((ext_vector_type(8))) short      short8;
typedef __attribute__((ext_vector_type(4))) float      floatx4;

#define DI __device__ __forceinline__

constexpr int BB = 2, HH = 16, SS = 2048, DD = 64;
constexpr int TQ  = 64;            // q rows per workgroup (16 per wave, 4 waves)
constexpr int TK  = 64;            // kv per tile
constexpr int NKT = SS / TK;       // 32 kv tiles
constexpr int PITCH = 72;          // LDS row pitch (elements); 144B rows keep 16B align

DI unsigned short f2bfu(float f) {
    __hip_bfloat16 h = __float2bfloat16(f);
    return __builtin_bit_cast(unsigned short, h);
}

// load 8 consecutive f32, round to bf16, pack into an MFMA half-fragment
DI short8 cvt8(const float* __restrict__ p) {
    floatx4 a = *(const floatx4*)p;
    floatx4 b = *(const floatx4*)(p + 4);
    short8 r;
    r[0] = (short)f2bfu(a[0]); r[1] = (short)f2bfu(a[1]);
    r[2] = (short)f2bfu(a[2]); r[3] = (short)f2bfu(a[3]);
    r[4] = (short)f2bfu(b[0]); r[5] = (short)f2bfu(b[1]);
    r[6] = (short)f2bfu(b[2]); r[7] = (short)f2bfu(b[3]);
    return r;
}

__global__ __launch_bounds__(256, 2)
void sdpa_kernel(const float* __restrict__ Q,
                 const float* __restrict__ K,
                 const float* __restrict__ V,
                 const int*   __restrict__ mask,
                 float*       __restrict__ out_ctx,
                 float*       __restrict__ out_w)
{
    __shared__ __align__(16) unsigned short Vt[DD * PITCH];  // V^T tile (bf16): Vt[d][kv]
    __shared__ __align__(16) unsigned short Pl[TQ * PITCH];  // P tile  (bf16): Pl[q_local][kv]

    const int tid  = (int)threadIdx.x;
    const int wave = tid >> 6;
    const int lane = tid & 63;
    const int quad = lane >> 4;
    const int col  = lane & 15;

    const int bh = (int)blockIdx.y;      // 0..31 (b*16 + h)
    const int b  = bh >> 4;
    const int q0 = (int)blockIdx.x * TQ;
    const int qw = q0 + wave * 16;       // this wave's 16 q-rows

    const size_t head = (size_t)bh * SS * DD;
    const float* Qh = Q + head;
    const float* Kh = K + head;
    const float* Vh = V + head;
    const int*   Mb = mask  + (size_t)b  * SS * SS;
    float*       Wh = out_w + (size_t)bh * SS * SS;

    // ---- Q A-fragments (bf16, held in regs for the whole kernel) ----
    // A[m=lane&15][k=quad*8+j], k-chunks 0 and 32
    short8 aQ0, aQ1;
    {
        const float* qp = Qh + (size_t)(qw + col) * DD + quad * 8;
        aQ0 = cvt8(qp);
        aQ1 = cvt8(qp + 32);
    }

    // =============== Pass 1: online per-lane (m, l) ===============
    float mrow[4], lrow[4];
#pragma unroll
    for (int r = 0; r < 4; ++r) { mrow[r] = -__builtin_inff(); lrow[r] = 0.f; }

    for (int kt = 0; kt < NKT; ++kt) {
        const int kv0 = kt * TK;
        floatx4 acc[4];
#pragma unroll
        for (int nt = 0; nt < 4; ++nt) {
            const float* kp = Kh + (size_t)(kv0 + nt * 16 + col) * DD + quad * 8;
            short8 b0 = cvt8(kp);
            short8 b1 = cvt8(kp + 32);
            floatx4 a = {0.f, 0.f, 0.f, 0.f};
            a = __builtin_amdgcn_mfma_f32_16x16x32_bf16(aQ0, b0, a, 0, 0, 0);
            a = __builtin_amdgcn_mfma_f32_16x16x32_bf16(aQ1, b1, a, 0, 0, 0);
            acc[nt] = a;
        }
#pragma unroll
        for (int r = 0; r < 4; ++r) {
            const int q = qw + quad * 4 + r;
            const int* mp = Mb + (size_t)q * SS + kv0 + col;
            float s0 = acc[0][r] * 0.125f; s0 = (mp[0]  != 0) ? s0 : -1e9f;
            float s1 = acc[1][r] * 0.125f; s1 = (mp[16] != 0) ? s1 : -1e9f;
            float s2 = acc[2][r] * 0.125f; s2 = (mp[32] != 0) ? s2 : -1e9f;
            float s3 = acc[3][r] * 0.125f; s3 = (mp[48] != 0) ? s3 : -1e9f;
            float lm = fmaxf(fmaxf(s0, s1), fmaxf(s2, s3));
            float mn = fmaxf(mrow[r], lm);
            float p  = __expf(s0 - mn) + __expf(s1 - mn) + __expf(s2 - mn) + __expf(s3 - mn);
            lrow[r]  = lrow[r] * __expf(mrow[r] - mn) + p;   // 0 * exp(-inf) = 0 on first tile
            mrow[r]  = mn;
        }
    }
    // merge (m,l) across the 16 lanes of each quad-group (those share rows quad*4+r)
#pragma unroll
    for (int r = 0; r < 4; ++r) {
#pragma unroll
        for (int off = 1; off < 16; off <<= 1) {
            float mo = __shfl_xor(mrow[r], off);
            float lo = __shfl_xor(lrow[r], off);
            float mn = fmaxf(mrow[r], mo);
            lrow[r] = lrow[r] * __expf(mrow[r] - mn) + lo * __expf(mo - mn);
            mrow[r] = mn;
        }
    }
    float rl[4];
#pragma unroll
    for (int r = 0; r < 4; ++r) rl[r] = 1.0f / lrow[r];

    // =============== Pass 2: recompute, write f32 weights, fuse PV ===============
    floatx4 ctx[4];
#pragma unroll
    for (int nt = 0; nt < 4; ++nt) ctx[nt] = floatx4{0.f, 0.f, 0.f, 0.f};

    for (int kt = 0; kt < NKT; ++kt) {
        const int kv0 = kt * TK;

        // recompute scores (K re-read from global; L2-hot)
        floatx4 acc[4];
#pragma unroll
        for (int nt = 0; nt < 4; ++nt) {
            const float* kp = Kh + (size_t)(kv0 + nt * 16 + col) * DD + quad * 8;
            short8 b0 = cvt8(kp);
            short8 b1 = cvt8(kp + 32);
            floatx4 a = {0.f, 0.f, 0.f, 0.f};
            a = __builtin_amdgcn_mfma_f32_16x16x32_bf16(aQ0, b0, a, 0, 0, 0);
            a = __builtin_amdgcn_mfma_f32_16x16x32_bf16(aQ1, b1, a, 0, 0, 0);
            acc[nt] = a;
        }

        __syncthreads();   // previous iteration's LDS reads are done

        // stage V^T cooperatively: thread -> one kv row, 16 d's (f32 load -> bf16 LDS)
        {
            const int kvr = tid >> 2;          // 0..63
            const int d0  = (tid & 3) * 16;    // 0,16,32,48
            const float* vp = Vh + (size_t)(kv0 + kvr) * DD + d0;
            floatx4 v0 = *(const floatx4*)vp;
            floatx4 v1 = *(const floatx4*)(vp + 4);
            floatx4 v2 = *(const floatx4*)(vp + 8);
            floatx4 v3 = *(const floatx4*)(vp + 12);
#pragma unroll
            for (int i = 0; i < 4; ++i) Vt[(d0 + i)      * PITCH + kvr] = f2bfu(v0[i]);
#pragma unroll
            for (int i = 0; i < 4; ++i) Vt[(d0 + 4 + i)  * PITCH + kvr] = f2bfu(v1[i]);
#pragma unroll
            for (int i = 0; i < 4; ++i) Vt[(d0 + 8 + i)  * PITCH + kvr] = f2bfu(v2[i]);
#pragma unroll
            for (int i = 0; i < 4; ++i) Vt[(d0 + 12 + i) * PITCH + kvr] = f2bfu(v3[i]);
        }

        // normalized weights: f32 -> global directly, bf16 -> Pl for the PV MFMA
#pragma unroll
        for (int r = 0; r < 4; ++r) {
            const int q = qw + quad * 4 + r;
            const int* mp = Mb + (size_t)q * SS + kv0 + col;
            float* wp = Wh + (size_t)q * SS + kv0 + col;
#pragma unroll
            for (int nt = 0; nt < 4; ++nt) {
                float v = acc[nt][r] * 0.125f;
                v = (mp[nt * 16] != 0) ? v : -1e9f;
                float w = __expf(v - mrow[r]) * rl[r];
                wp[nt * 16] = w;
                Pl[(wave * 16 + quad * 4 + r) * PITCH + nt * 16 + col] = f2bfu(w);
            }
        }

        __syncthreads();

        // PV MFMA: A = P from LDS, B = V^T from LDS
        short8 pA0 = *(const short8*)&Pl[(wave * 16 + col) * PITCH + quad * 8];
        short8 pA1 = *(const short8*)&Pl[(wave * 16 + col) * PITCH + 32 + quad * 8];
#pragma unroll
        for (int nt = 0; nt < 4; ++nt) {
            short8 vB0 = *(const short8*)&Vt[(nt * 16 + col) * PITCH + quad * 8];
            short8 vB1 = *(const short8*)&Vt[(nt * 16 + col) * PITCH + 32 + quad * 8];
            ctx[nt] = __builtin_amdgcn_mfma_f32_16x16x32_bf16(pA0, vB0, ctx[nt], 0, 0, 0);
            ctx[nt] = __builtin_amdgcn_mfma_f32_16x16x32_bf16(pA1, vB1, ctx[nt], 0, 0, 0);
        }
    }

    // ---- context epilogue (f32 stores) ----
#pragma unroll
    for (int nt = 0; nt < 4; ++nt) {
#pragma unroll
        for (int r = 0; r < 4; ++r) {
            const int q = qw + quad * 4 + r;
            out_ctx[head + (size_t)q * DD + nt * 16 + col] = ctx[nt][r];
        }
    }
}

extern "C" void kernel_launch(void* const* d_in, const int* in_sizes, int n_in,
                              void* d_out, int out_size, void* d_ws, size_t ws_size,
                              hipStream_t stream) {
    const float* Q = (const float*)d_in[0];
    const float* K = (const float*)d_in[1];
    const float* V = (const float*)d_in[2];
    const int* mask = (const int*)d_in[3];

    float* out     = (float*)d_out;
    float* out_ctx = out;                               // [B,H,S,D]
    float* out_w   = out + (size_t)BB * HH * SS * DD;   // [B,H,S,S]

    dim3 grid(SS / TQ, BB * HH);   // (32, 32)
    hipLaunchKernelGGL(sdpa_kernel, grid, dim3(256), 0, stream,
                       Q, K, V, mask, out_ctx, out_w);
}